// Round 3
// baseline (501.793 us; speedup 1.0000x reference)
//
#include <hip/hip_runtime.h>

#define NEDGES 20000
#define KMAX 16
#define NTRIP (NEDGES*KMAX)
#define EMB 128
#define INTERM 64
#define NSPH 7
#define UNITS 128
#define KSTEPS 256               // K = 8192 / 32

#define SC_BLOCKS (NTRIP/256)    // 1250
#define W_BLOCKS  512
#define RP_BLOCKS (NEDGES/4)     // 5000

typedef __attribute__((ext_vector_type(8))) short short8;
typedef __attribute__((ext_vector_type(4))) float floatx4;
typedef __attribute__((ext_vector_type(2))) float v2f;

__device__ __forceinline__ unsigned bf16pair(float a, float b) {
    unsigned ua = __float_as_uint(a), ub = __float_as_uint(b);
    ua = (ua + 0x7fffu + ((ua >> 16) & 1u)) >> 16;
    ub = (ub + 0x7fffu + ((ub >> 16) & 1u)) & 0xffff0000u;
    return ua | ub;
}
__device__ __forceinline__ v2f splat2(float f) { v2f r; r.x = f; r.y = f; return r; }

// prep roles: [0,1250) scatter-inverse; [1250,1762) weight->bf16 B-frags;
// [1762,6762) rbf fp32 (e,i,7) -> bf16 rpad2[i][e] (8 bf16 = uint4, transposed
// so fused_all's per-chunk wave read is 16 consecutive edges = contiguous).
// No memset needed: (id_reduce,Kidx) pairs cover all slots; fused_all also
// bounds-checks t.
__global__ __launch_bounds__(256)
void prep(const int* __restrict__ idr, const int* __restrict__ kix,
          int* __restrict__ inv, const float* __restrict__ w,
          uint4* __restrict__ w2f, const float* __restrict__ rbf,
          uint4* __restrict__ rpad2) {
    const int b = blockIdx.x, tid = threadIdx.x;
    if (b < SC_BLOCKS) {
        int t = b * 256 + tid;
        int e = idr[t], k = kix[t];
        if ((unsigned)e < NEDGES && (unsigned)k < KMAX)
            inv[e * KMAX + k] = t;
    } else if (b < SC_BLOCKS + W_BLOCKS) {
        // weight (emb, interm, o) fp32 -> bf16 MFMA B-fragment order.
        // uint4 idx = (nt*256 + ks)*64 + lane; elem j: k = ks*32 + (lane>>4)*8 + j,
        // o = nt*16 + (lane&15); k = i*128 + emb.
        int idx  = (b - SC_BLOCKS) * 256 + tid;
        int lane = idx & 63;
        int ks   = (idx >> 6) & 255;
        int nt   = idx >> 14;
        int o  = nt * 16 + (lane & 15);
        int kb = ks * 32 + (lane >> 4) * 8;
        unsigned pk[4];
#pragma unroll
        for (int jj = 0; jj < 4; ++jj) {
            int k0 = kb + 2 * jj;
            int i0 = k0 >> 7, em0 = k0 & 127;
            int i1 = (k0 + 1) >> 7, em1 = (k0 + 1) & 127;
            float f0 = w[((size_t)em0 * INTERM + i0) * UNITS + o];
            float f1 = w[((size_t)em1 * INTERM + i1) * UNITS + o];
            pk[jj] = bf16pair(f0, f1);
        }
        w2f[idx] = make_uint4(pk[0], pk[1], pk[2], pk[3]);
    } else {
        // rpad2: thread (e = rb*4 + (tid&3), i = tid>>2); 4-lane groups write
        // 64B contiguous (consecutive e) per i.
        int rb = b - (SC_BLOCKS + W_BLOCKS);
        int e = rb * 4 + (tid & 3), i = tid >> 2;
        const float* rs = rbf + (size_t)e * 448 + i * 7;
        float s0 = rs[0], s1 = rs[1], s2 = rs[2], s3 = rs[3];
        float s4 = rs[4], s5 = rs[5], s6 = rs[6];
        rpad2[(size_t)i * NEDGES + e] = make_uint4(bf16pair(s0, s1), bf16pair(s2, s3),
                                                   bf16pair(s4, s5), bf16pair(s6, 0.f));
    }
}

// fused_all: block = 32 edges x N=128 x full K. 512 threads (8 waves, wave = nt).
// Thread ownership chosen so wave wid builds exactly a_s frag-row wid:
//   eo = (wid>>2)*16 + (lane&15), oco = (wid&3)*4 + (lane>>4).
// Then BOTH the a_s write (wid*65+lane) and reads (fr*65+lane) are the
// canonical 64-consecutive-uint4 pattern -> conflict-free, no swizzle.
// Prologue: skf[7][8] (edge eo, embs oco*8..+7) accumulated from m/sph via inv
// (t's preloaded, 2-deep m pipeline). Main loop: 64 chunks of one interm i;
// A-frags built from rpad2 (reg prefetch) + skf into LDS double buffer;
// B-frags (w2f) loaded post-barrier.
__global__ __launch_bounds__(512, 4)
void fused_all(const float* __restrict__ sph, const float* __restrict__ m,
               const int* __restrict__ inv, const uint4* __restrict__ w2f,
               const uint4* __restrict__ rpad2, float* __restrict__ out) {
    __shared__ uint4 a_s[2][520];                 // 16640 B, frag-row stride 65
    int*   inv_s = (int*)a_s;                     // scratch: 32x17 ints = 2176 B
    float* sph_s = (float*)((char*)a_s + 2176);   // scratch: 32x113 f32 = 14464 B

    const int tid = threadIdx.x;
    const size_t e0 = (size_t)blockIdx.x * 32;
    const int lane = tid & 63, wid = tid >> 6;    // wid = nt 0..7
    const int eo  = (wid >> 2) * 16 + (lane & 15);   // owned edge 0..31
    const int oco = (wid & 3) * 4 + (lane >> 4);     // owned emb octet 0..15

    // stage inv + sph into padded scratch (odd strides 17/113: conflict-free)
    {
        int e = tid >> 4, k = tid & 15;
        inv_s[e * 17 + k] = inv[e0 * 16 + tid];
    }
    for (int j = tid; j < 32 * 112; j += 512) {
        int e = j / 112, r = j - e * 112;
        sph_s[e * 113 + r] = sph[e0 * 112 + j];
    }

    // long-latency prefetches hidden under the prologue
    floatx4 acc[2] = {{0.f, 0.f, 0.f, 0.f}, {0.f, 0.f, 0.f, 0.f}};
    uint4 wf[4];
    const uint4* wbase = w2f + ((size_t)wid * KSTEPS) * 64 + lane;
#pragma unroll
    for (int ksl = 0; ksl < 4; ++ksl) wf[ksl] = wbase[(size_t)ksl * 64];
    const uint4* rpg = rpad2 + (e0 + eo);
    uint4 rpA = rpg[0], rpB = rpg[(size_t)1 * NEDGES];

    __syncthreads();

    // fused build_sumk: skf[s][h] = sum_k sph[eo][s][k] * m[inv[eo][k]][oco*8+2h..+1]
    v2f skf[NSPH][4];
#pragma unroll
    for (int s = 0; s < NSPH; ++s)
#pragma unroll
        for (int h = 0; h < 4; ++h) skf[s][h] = splat2(0.f);
    {
        const float4* mrow = (const float4*)m;
        const float* sp = sph_s + eo * 113;
        int tpre[16];
#pragma unroll
        for (int k = 0; k < 16; ++k) tpre[k] = inv_s[eo * 17 + k];

        float4 c0 = make_float4(0.f, 0.f, 0.f, 0.f), c1 = c0;
        {
            int t = tpre[0];
            if ((unsigned)t < (unsigned)NTRIP) {
                const float4* tp = mrow + (size_t)t * 32 + oco * 2;
                c0 = tp[0]; c1 = tp[1];
            }
        }
#pragma unroll
        for (int k = 0; k < 16; ++k) {
            float4 n0 = make_float4(0.f, 0.f, 0.f, 0.f), n1 = n0;
            if (k < 15) {
                int t = tpre[k + 1];
                if ((unsigned)t < (unsigned)NTRIP) {
                    const float4* tp = mrow + (size_t)t * 32 + oco * 2;
                    n0 = tp[0]; n1 = tp[1];
                }
            }
            v2f mv[4];
            mv[0].x = c0.x; mv[0].y = c0.y;
            mv[1].x = c0.z; mv[1].y = c0.w;
            mv[2].x = c1.x; mv[2].y = c1.y;
            mv[3].x = c1.z; mv[3].y = c1.w;
#pragma unroll
            for (int s = 0; s < NSPH; ++s) {
                float cs = sp[s * 16 + k];
#pragma unroll
                for (int h = 0; h < 4; ++h)
                    skf[s][h] = __builtin_elementwise_fma(splat2(cs), mv[h], skf[s][h]);
            }
            c0 = n0; c1 = n1;
        }
    }

    // build one A-frag uint4 (edge eo, embs oco*8..+7, interm chunk rv4) at
    // a_s unit wid*65+lane (contiguous per wave -> conflict-free)
    auto buildChunk = [&](const uint4 rv4, uint4* dstbuf) {
        float rv[NSPH];
        rv[0] = __uint_as_float(rv4.x << 16);
        rv[1] = __uint_as_float(rv4.x & 0xffff0000u);
        rv[2] = __uint_as_float(rv4.y << 16);
        rv[3] = __uint_as_float(rv4.y & 0xffff0000u);
        rv[4] = __uint_as_float(rv4.z << 16);
        rv[5] = __uint_as_float(rv4.z & 0xffff0000u);
        rv[6] = __uint_as_float(rv4.w << 16);
        v2f v[4];
#pragma unroll
        for (int h = 0; h < 4; ++h) v[h] = splat2(rv[0]) * skf[0][h];
#pragma unroll
        for (int s = 1; s < NSPH; ++s)
#pragma unroll
            for (int h = 0; h < 4; ++h)
                v[h] = __builtin_elementwise_fma(splat2(rv[s]), skf[s][h], v[h]);
        dstbuf[wid * 65 + lane] = make_uint4(bf16pair(v[0].x, v[0].y), bf16pair(v[1].x, v[1].y),
                                             bf16pair(v[2].x, v[2].y), bf16pair(v[3].x, v[3].y));
    };

    auto mfmaStep = [&](const uint4* abuf) {
#pragma unroll
        for (int ksl = 0; ksl < 4; ++ksl) {
            short8 a0 = __builtin_bit_cast(short8, abuf[ksl * 65 + lane]);
            short8 a1 = __builtin_bit_cast(short8, abuf[(4 + ksl) * 65 + lane]);
            short8 bb = __builtin_bit_cast(short8, wf[ksl]);
            acc[0] = __builtin_amdgcn_mfma_f32_16x16x32_bf16(a0, bb, acc[0], 0, 0, 0);
            acc[1] = __builtin_amdgcn_mfma_f32_16x16x32_bf16(a1, bb, acc[1], 0, 0, 0);
        }
    };

    __syncthreads();            // scratch (inv_s/sph_s) dead; a_s reusable
    buildChunk(rpA, a_s[0]);    // chunk 0
    rpA = rpg[(size_t)2 * NEDGES];
    __syncthreads();

    for (int c = 0; c < 64; c += 2) {
        // even: MFMA chunk c (buf0), build chunk c+1 (buf1)
        buildChunk(rpB, a_s[1]);
        if (c + 3 < 64) rpB = rpg[(size_t)(c + 3) * NEDGES];
        mfmaStep(a_s[0]);
        __syncthreads();
#pragma unroll
        for (int ksl = 0; ksl < 4; ++ksl)      // post-barrier B-frags, chunk c+1
            wf[ksl] = wbase[(size_t)((c + 1) * 4 + ksl) * 64];

        // odd: MFMA chunk c+1 (buf1), build chunk c+2 (buf0)
        if (c + 2 < 64) {
            buildChunk(rpA, a_s[0]);
            if (c + 4 < 64) rpA = rpg[(size_t)(c + 4) * NEDGES];
        }
        mfmaStep(a_s[1]);
        __syncthreads();
        if (c + 2 < 64) {
#pragma unroll
            for (int ksl = 0; ksl < 4; ++ksl)  // post-barrier B-frags, chunk c+2
                wf[ksl] = wbase[(size_t)((c + 2) * 4 + ksl) * 64];
        }
    }

    // epilogue: C/D col = lane&15, row = (lane>>4)*4 + r
    const int col = lane & 15, r0 = (lane >> 4) * 4;
#pragma unroll
    for (int h = 0; h < 2; ++h) {
        size_t ebase = e0 + (size_t)h * 16 + r0;
#pragma unroll
        for (int r = 0; r < 4; ++r)
            out[(ebase + r) * UNITS + wid * 16 + col] = acc[h][r];
    }
}

extern "C" void kernel_launch(void* const* d_in, const int* in_sizes, int n_in,
                              void* d_out, int out_size, void* d_ws, size_t ws_size,
                              hipStream_t stream) {
    const float* rbf = (const float*)d_in[0];
    const float* sph = (const float*)d_in[1];
    const float* m   = (const float*)d_in[2];
    const float* w   = (const float*)d_in[3];
    const int*   idr = (const int*)d_in[4];
    const int*   kix = (const int*)d_in[5];
    float* out = (float*)d_out;

    // ws: inv (1.28 MB, pad to 0x140000) | w2f (2 MB) | rpad2 (20.48 MB)
    int*   inv   = (int*)d_ws;
    uint4* w2f   = (uint4*)((char*)d_ws + 0x140000);
    uint4* rpad2 = (uint4*)((char*)d_ws + 0x340000);

    prep<<<SC_BLOCKS + W_BLOCKS + RP_BLOCKS, 256, 0, stream>>>(idr, kix, inv, w, w2f, rbf, rpad2);
    fused_all<<<NEDGES / 32, 512, 0, stream>>>(sph, m, inv, w2f, rpad2, out);
}

// Round 4
// 426.381 us; speedup vs baseline: 1.1769x; 1.1769x over previous
//
#include <hip/hip_runtime.h>

#define NEDGES 20000
#define KMAX 16
#define NTRIP (NEDGES*KMAX)
#define EMB 128
#define INTERM 64
#define NSPH 7
#define UNITS 128
#define KSTEPS 256               // K = 8192 / 32

#define SC_BLOCKS (NTRIP/256)    // 1250
#define W_BLOCKS  512
#define RP_BLOCKS (NEDGES/16)    // 1250

typedef __attribute__((ext_vector_type(8))) short short8;
typedef __attribute__((ext_vector_type(4))) float floatx4;
typedef __attribute__((ext_vector_type(2))) float v2f;

__device__ __forceinline__ unsigned bf16pair(float a, float b) {
    unsigned ua = __float_as_uint(a), ub = __float_as_uint(b);
    ua = (ua + 0x7fffu + ((ua >> 16) & 1u)) >> 16;
    ub = (ub + 0x7fffu + ((ub >> 16) & 1u)) & 0xffff0000u;
    return ua | ub;
}
__device__ __forceinline__ v2f splat2(float f) { v2f r; r.x = f; r.y = f; return r; }

// prep roles: [0,1250) scatter-inverse; [1250,1762) weight->bf16 B-frags;
// [1762,3012) rbf fp32 (e,i,7) -> bf16 rpad2[i][e], LDS-staged per 16 edges
// (coalesced float4 reads; padded-stride LDS; 256B-chunk writes).
// No memset needed: (id_reduce,Kidx) pairs cover all slots; fused_all also
// bounds-checks t.
__global__ __launch_bounds__(256)
void prep(const int* __restrict__ idr, const int* __restrict__ kix,
          int* __restrict__ inv, const float* __restrict__ w,
          uint4* __restrict__ w2f, const float* __restrict__ rbf,
          uint4* __restrict__ rpad2) {
    __shared__ float lr[16 * 452];    // 28.9 KB, stride 452 (16B-aligned, 2-way banks)
    const int b = blockIdx.x, tid = threadIdx.x;
    if (b < SC_BLOCKS) {
        int t = b * 256 + tid;
        int e = idr[t], k = kix[t];
        if ((unsigned)e < NEDGES && (unsigned)k < KMAX)
            inv[e * KMAX + k] = t;
    } else if (b < SC_BLOCKS + W_BLOCKS) {
        // weight (emb, interm, o) fp32 -> bf16 MFMA B-fragment order.
        // uint4 idx = (nt*256 + ks)*64 + lane; elem j: k = ks*32 + (lane>>4)*8 + j,
        // o = nt*16 + (lane&15); k = i*128 + emb.
        int idx  = (b - SC_BLOCKS) * 256 + tid;
        int lane = idx & 63;
        int ks   = (idx >> 6) & 255;
        int nt   = idx >> 14;
        int o  = nt * 16 + (lane & 15);
        int kb = ks * 32 + (lane >> 4) * 8;
        unsigned pk[4];
#pragma unroll
        for (int jj = 0; jj < 4; ++jj) {
            int k0 = kb + 2 * jj;
            int i0 = k0 >> 7, em0 = k0 & 127;
            int i1 = (k0 + 1) >> 7, em1 = (k0 + 1) & 127;
            float f0 = w[((size_t)em0 * INTERM + i0) * UNITS + o];
            float f1 = w[((size_t)em1 * INTERM + i1) * UNITS + o];
            pk[jj] = bf16pair(f0, f1);
        }
        w2f[idx] = make_uint4(pk[0], pk[1], pk[2], pk[3]);
    } else {
        int rb = b - (SC_BLOCKS + W_BLOCKS);
        const float4* rg = (const float4*)(rbf + (size_t)rb * 16 * 448);
        for (int j = tid; j < 1792; j += 256) {
            float4 v = rg[j];
            int e = j / 112, idx = j - e * 112;
            *(float4*)&lr[e * 452 + idx * 4] = v;
        }
        __syncthreads();
        int e = tid & 15, ib = tid >> 4;
#pragma unroll
        for (int r = 0; r < 4; ++r) {
            int i = r * 16 + ib;
            const float* s = &lr[e * 452 + i * 7];
            rpad2[(size_t)i * NEDGES + rb * 16 + e] =
                make_uint4(bf16pair(s[0], s[1]), bf16pair(s[2], s[3]),
                           bf16pair(s[4], s[5]), bf16pair(s[6], 0.f));
        }
    }
}

// fused_all: block = 32 edges x N=128 x full K. 512 threads (8 waves, wave = nt).
// Thread ownership chosen so wave wid builds exactly a_s frag-row wid:
//   eo = (wid>>2)*16 + (lane&15), oco = (wid&3)*4 + (lane>>4).
// Then BOTH the a_s write (wid*65+lane) and reads (fr*65+lane) are the
// canonical 64-consecutive-uint4 pattern -> conflict-free, no swizzle.
// NO min-occupancy clamp: main-loop live state is ~110 VGPRs (skf 56 + wf 16
// + acc + rp + addressing); the old __launch_bounds__(512,4) capped the
// allocator at 64 and produced ~290 MB/dispatch of scratch spill (R3 counters).
__global__ __launch_bounds__(512)
void fused_all(const float* __restrict__ sph, const float* __restrict__ m,
               const int* __restrict__ inv, const uint4* __restrict__ w2f,
               const uint4* __restrict__ rpad2, float* __restrict__ out) {
    __shared__ uint4 a_s[2][520];                 // 16640 B, frag-row stride 65
    int*   inv_s = (int*)a_s;                     // scratch: 32x17 ints = 2176 B
    float* sph_s = (float*)((char*)a_s + 2176);   // scratch: 32x113 f32 = 14464 B

    const int tid = threadIdx.x;
    const size_t e0 = (size_t)blockIdx.x * 32;
    const int lane = tid & 63, wid = tid >> 6;    // wid = nt 0..7
    const int eo  = (wid >> 2) * 16 + (lane & 15);   // owned edge 0..31
    const int oco = (wid & 3) * 4 + (lane >> 4);     // owned emb octet 0..15

    // stage inv + sph into padded scratch (odd strides 17/113: conflict-free)
    {
        int e = tid >> 4, k = tid & 15;
        inv_s[e * 17 + k] = inv[e0 * 16 + tid];
    }
    for (int j = tid; j < 32 * 112; j += 512) {
        int e = j / 112, r = j - e * 112;
        sph_s[e * 113 + r] = sph[e0 * 112 + j];
    }
    __syncthreads();

    // long-latency prefetches issued here so they hide under the m-gather
    // (and are NOT drained by the staging barrier above)
    floatx4 acc[2] = {{0.f, 0.f, 0.f, 0.f}, {0.f, 0.f, 0.f, 0.f}};
    uint4 wf[4];
    const uint4* wbase = w2f + ((size_t)wid * KSTEPS) * 64 + lane;
#pragma unroll
    for (int ksl = 0; ksl < 4; ++ksl) wf[ksl] = wbase[(size_t)ksl * 64];
    const uint4* rpg = rpad2 + (e0 + eo);
    uint4 rpA = rpg[0], rpB = rpg[(size_t)1 * NEDGES];

    // fused build_sumk: skf[s][h] = sum_k sph[eo][s][k] * m[inv[eo][k]][oco*8+2h..+1]
    // 2-deep m pipeline; inv read per-k from LDS (prologue-only liveness).
    v2f skf[NSPH][4];
#pragma unroll
    for (int s = 0; s < NSPH; ++s)
#pragma unroll
        for (int h = 0; h < 4; ++h) skf[s][h] = splat2(0.f);
    {
        const float4* mrow = (const float4*)m;
        const int* ipd = inv_s + eo * 17;
        const float* sp = sph_s + eo * 113;

        float4 c0 = make_float4(0.f, 0.f, 0.f, 0.f), c1 = c0;
        {
            int t = ipd[0];
            if ((unsigned)t < (unsigned)NTRIP) {
                const float4* tp = mrow + (size_t)t * 32 + oco * 2;
                c0 = tp[0]; c1 = tp[1];
            }
        }
#pragma unroll
        for (int k = 0; k < 16; ++k) {
            float4 n0 = make_float4(0.f, 0.f, 0.f, 0.f), n1 = n0;
            if (k < 15) {
                int t = ipd[k + 1];
                if ((unsigned)t < (unsigned)NTRIP) {
                    const float4* tp = mrow + (size_t)t * 32 + oco * 2;
                    n0 = tp[0]; n1 = tp[1];
                }
            }
            v2f mv[4];
            mv[0].x = c0.x; mv[0].y = c0.y;
            mv[1].x = c0.z; mv[1].y = c0.w;
            mv[2].x = c1.x; mv[2].y = c1.y;
            mv[3].x = c1.z; mv[3].y = c1.w;
#pragma unroll
            for (int s = 0; s < NSPH; ++s) {
                float cs = sp[s * 16 + k];
#pragma unroll
                for (int h = 0; h < 4; ++h)
                    skf[s][h] = __builtin_elementwise_fma(splat2(cs), mv[h], skf[s][h]);
            }
            c0 = n0; c1 = n1;
        }
    }

    // build one A-frag uint4 (edge eo, embs oco*8..+7, interm chunk rv4) at
    // a_s unit wid*65+lane (contiguous per wave -> conflict-free)
    auto buildChunk = [&](const uint4 rv4, uint4* dstbuf) {
        float rv[NSPH];
        rv[0] = __uint_as_float(rv4.x << 16);
        rv[1] = __uint_as_float(rv4.x & 0xffff0000u);
        rv[2] = __uint_as_float(rv4.y << 16);
        rv[3] = __uint_as_float(rv4.y & 0xffff0000u);
        rv[4] = __uint_as_float(rv4.z << 16);
        rv[5] = __uint_as_float(rv4.z & 0xffff0000u);
        rv[6] = __uint_as_float(rv4.w << 16);
        v2f v[4];
#pragma unroll
        for (int h = 0; h < 4; ++h) v[h] = splat2(rv[0]) * skf[0][h];
#pragma unroll
        for (int s = 1; s < NSPH; ++s)
#pragma unroll
            for (int h = 0; h < 4; ++h)
                v[h] = __builtin_elementwise_fma(splat2(rv[s]), skf[s][h], v[h]);
        dstbuf[wid * 65 + lane] = make_uint4(bf16pair(v[0].x, v[0].y), bf16pair(v[1].x, v[1].y),
                                             bf16pair(v[2].x, v[2].y), bf16pair(v[3].x, v[3].y));
    };

    auto mfmaStep = [&](const uint4* abuf) {
#pragma unroll
        for (int ksl = 0; ksl < 4; ++ksl) {
            short8 a0 = __builtin_bit_cast(short8, abuf[ksl * 65 + lane]);
            short8 a1 = __builtin_bit_cast(short8, abuf[(4 + ksl) * 65 + lane]);
            short8 bb = __builtin_bit_cast(short8, wf[ksl]);
            acc[0] = __builtin_amdgcn_mfma_f32_16x16x32_bf16(a0, bb, acc[0], 0, 0, 0);
            acc[1] = __builtin_amdgcn_mfma_f32_16x16x32_bf16(a1, bb, acc[1], 0, 0, 0);
        }
    };

    __syncthreads();            // scratch (inv_s/sph_s) dead; a_s reusable
    buildChunk(rpA, a_s[0]);    // chunk 0
    rpA = rpg[(size_t)2 * NEDGES];
    __syncthreads();

    for (int c = 0; c < 64; c += 2) {
        // even: MFMA chunk c (buf0), build chunk c+1 (buf1)
        buildChunk(rpB, a_s[1]);
        if (c + 3 < 64) rpB = rpg[(size_t)(c + 3) * NEDGES];
        mfmaStep(a_s[0]);
        __syncthreads();
#pragma unroll
        for (int ksl = 0; ksl < 4; ++ksl)      // post-barrier B-frags, chunk c+1
            wf[ksl] = wbase[(size_t)((c + 1) * 4 + ksl) * 64];

        // odd: MFMA chunk c+1 (buf1), build chunk c+2 (buf0)
        if (c + 2 < 64) {
            buildChunk(rpA, a_s[0]);
            if (c + 4 < 64) rpA = rpg[(size_t)(c + 4) * NEDGES];
        }
        mfmaStep(a_s[1]);
        __syncthreads();
        if (c + 2 < 64) {
#pragma unroll
            for (int ksl = 0; ksl < 4; ++ksl)  // post-barrier B-frags, chunk c+2
                wf[ksl] = wbase[(size_t)((c + 2) * 4 + ksl) * 64];
        }
    }

    // epilogue: C/D col = lane&15, row = (lane>>4)*4 + r
    const int col = lane & 15, r0 = (lane >> 4) * 4;
#pragma unroll
    for (int h = 0; h < 2; ++h) {
        size_t ebase = e0 + (size_t)h * 16 + r0;
#pragma unroll
        for (int r = 0; r < 4; ++r)
            out[(ebase + r) * UNITS + wid * 16 + col] = acc[h][r];
    }
}

extern "C" void kernel_launch(void* const* d_in, const int* in_sizes, int n_in,
                              void* d_out, int out_size, void* d_ws, size_t ws_size,
                              hipStream_t stream) {
    const float* rbf = (const float*)d_in[0];
    const float* sph = (const float*)d_in[1];
    const float* m   = (const float*)d_in[2];
    const float* w   = (const float*)d_in[3];
    const int*   idr = (const int*)d_in[4];
    const int*   kix = (const int*)d_in[5];
    float* out = (float*)d_out;

    // ws: inv (1.28 MB, pad to 0x140000) | w2f (2 MB) | rpad2 (20.48 MB)
    int*   inv   = (int*)d_ws;
    uint4* w2f   = (uint4*)((char*)d_ws + 0x140000);
    uint4* rpad2 = (uint4*)((char*)d_ws + 0x340000);

    prep<<<SC_BLOCKS + W_BLOCKS + RP_BLOCKS, 256, 0, stream>>>(idr, kix, inv, w, w2f, rbf, rpad2);
    fused_all<<<NEDGES / 32, 512, 0, stream>>>(sph, m, inv, w2f, rpad2, out);
}

// Round 5
// 425.833 us; speedup vs baseline: 1.1784x; 1.0013x over previous
//
#include <hip/hip_runtime.h>

#define NEDGES 20000
#define KMAX 16
#define NTRIP (NEDGES*KMAX)
#define EMB 128
#define INTERM 64
#define NSPH 7
#define UNITS 128
#define KSTEPS 256               // K = 8192 / 32

#define SC_BLOCKS (NTRIP/256)    // 1250
#define W_BLOCKS  512
#define RP_BLOCKS (NEDGES/16)    // 1250

typedef __attribute__((ext_vector_type(8))) short short8;
typedef __attribute__((ext_vector_type(4))) float floatx4;
typedef __attribute__((ext_vector_type(2))) float v2f;

__device__ __forceinline__ unsigned bf16pair(float a, float b) {
    unsigned ua = __float_as_uint(a), ub = __float_as_uint(b);
    ua = (ua + 0x7fffu + ((ua >> 16) & 1u)) >> 16;
    ub = (ub + 0x7fffu + ((ub >> 16) & 1u)) & 0xffff0000u;
    return ua | ub;
}
__device__ __forceinline__ v2f splat2(float f) { v2f r; r.x = f; r.y = f; return r; }

// prep roles: [0,1250) scatter-inverse; [1250,1762) weight->bf16 B-frags;
// [1762,3012) rbf fp32 (e,i,7) -> bf16 rpad2[i][e], LDS-staged per 16 edges
// (coalesced float4 reads; padded-stride LDS; 256B-chunk writes).
// No memset needed: (id_reduce,Kidx) pairs cover all slots; fused_all also
// bounds-checks t.
__global__ __launch_bounds__(256)
void prep(const int* __restrict__ idr, const int* __restrict__ kix,
          int* __restrict__ inv, const float* __restrict__ w,
          uint4* __restrict__ w2f, const float* __restrict__ rbf,
          uint4* __restrict__ rpad2) {
    __shared__ float lr[16 * 452];    // 28.9 KB, stride 452 (16B-aligned, 2-way banks)
    const int b = blockIdx.x, tid = threadIdx.x;
    if (b < SC_BLOCKS) {
        int t = b * 256 + tid;
        int e = idr[t], k = kix[t];
        if ((unsigned)e < NEDGES && (unsigned)k < KMAX)
            inv[e * KMAX + k] = t;
    } else if (b < SC_BLOCKS + W_BLOCKS) {
        // weight (emb, interm, o) fp32 -> bf16 MFMA B-fragment order.
        // uint4 idx = (nt*256 + ks)*64 + lane; elem j: k = ks*32 + (lane>>4)*8 + j,
        // o = nt*16 + (lane&15); k = i*128 + emb.
        int idx  = (b - SC_BLOCKS) * 256 + tid;
        int lane = idx & 63;
        int ks   = (idx >> 6) & 255;
        int nt   = idx >> 14;
        int o  = nt * 16 + (lane & 15);
        int kb = ks * 32 + (lane >> 4) * 8;
        unsigned pk[4];
#pragma unroll
        for (int jj = 0; jj < 4; ++jj) {
            int k0 = kb + 2 * jj;
            int i0 = k0 >> 7, em0 = k0 & 127;
            int i1 = (k0 + 1) >> 7, em1 = (k0 + 1) & 127;
            float f0 = w[((size_t)em0 * INTERM + i0) * UNITS + o];
            float f1 = w[((size_t)em1 * INTERM + i1) * UNITS + o];
            pk[jj] = bf16pair(f0, f1);
        }
        w2f[idx] = make_uint4(pk[0], pk[1], pk[2], pk[3]);
    } else {
        int rb = b - (SC_BLOCKS + W_BLOCKS);
        const float4* rg = (const float4*)(rbf + (size_t)rb * 16 * 448);
        for (int j = tid; j < 1792; j += 256) {
            float4 v = rg[j];
            int e = j / 112, idx = j - e * 112;
            *(float4*)&lr[e * 452 + idx * 4] = v;
        }
        __syncthreads();
        int e = tid & 15, ib = tid >> 4;
#pragma unroll
        for (int r = 0; r < 4; ++r) {
            int i = r * 16 + ib;
            const float* s = &lr[e * 452 + i * 7];
            rpad2[(size_t)i * NEDGES + rb * 16 + e] =
                make_uint4(bf16pair(s[0], s[1]), bf16pair(s[2], s[3]),
                           bf16pair(s[4], s[5]), bf16pair(s[6], 0.f));
        }
    }
}

// fused_all: block = 32 edges x N=128 x full K. 512 threads (8 waves, wave = nt).
// Thread ownership chosen so wave wid builds exactly a_s frag-row wid:
//   eo = (wid>>2)*16 + (lane&15), oco = (wid&3)*4 + (lane>>4).
// Then BOTH the a_s write (wid*65+lane) and reads (fr*65+lane) are the
// canonical 64-consecutive-uint4 pattern -> conflict-free, no swizzle.
// __launch_bounds__(512, 2): min 2 waves/EU -> VGPR cap 256. The live set is
// ~150 regs; R4's default heuristic capped at 128 and spilled ~81 MB/dispatch
// (WRITE_SIZE 91 MB vs 10 MB output). 2 waves/SIMD suffices: the per-chunk
// critical resource is the LDS pipe (~860 cyc/CU per chunk), not wave count.
__global__ __launch_bounds__(512, 2)
void fused_all(const float* __restrict__ sph, const float* __restrict__ m,
               const int* __restrict__ inv, const uint4* __restrict__ w2f,
               const uint4* __restrict__ rpad2, float* __restrict__ out) {
    __shared__ uint4 a_s[2][520];                 // 16640 B, frag-row stride 65
    int*   inv_s = (int*)a_s;                     // scratch: 32x17 ints = 2176 B
    float* sph_s = (float*)((char*)a_s + 2176);   // scratch: 32x113 f32 = 14464 B

    const int tid = threadIdx.x;
    const size_t e0 = (size_t)blockIdx.x * 32;
    const int lane = tid & 63, wid = tid >> 6;    // wid = nt 0..7
    const int eo  = (wid >> 2) * 16 + (lane & 15);   // owned edge 0..31
    const int oco = (wid & 3) * 4 + (lane >> 4);     // owned emb octet 0..15

    // stage inv + sph into padded scratch (odd strides 17/113: conflict-free)
    {
        int e = tid >> 4, k = tid & 15;
        inv_s[e * 17 + k] = inv[e0 * 16 + tid];
    }
    for (int j = tid; j < 32 * 112; j += 512) {
        int e = j / 112, r = j - e * 112;
        sph_s[e * 113 + r] = sph[e0 * 112 + j];
    }
    __syncthreads();

    // long-latency prefetches issued here so they hide under the m-gather
    // (and are NOT drained by the staging barrier above)
    floatx4 acc[2] = {{0.f, 0.f, 0.f, 0.f}, {0.f, 0.f, 0.f, 0.f}};
    uint4 wf[4];
    const uint4* wbase = w2f + ((size_t)wid * KSTEPS) * 64 + lane;
#pragma unroll
    for (int ksl = 0; ksl < 4; ++ksl) wf[ksl] = wbase[(size_t)ksl * 64];
    const uint4* rpg = rpad2 + (e0 + eo);
    uint4 rpA = rpg[0], rpB = rpg[(size_t)1 * NEDGES];

    // fused build_sumk: skf[s][h] = sum_k sph[eo][s][k] * m[inv[eo][k]][oco*8+2h..+1]
    // 2-deep m pipeline; inv read per-k from LDS (prologue-only liveness).
    v2f skf[NSPH][4];
#pragma unroll
    for (int s = 0; s < NSPH; ++s)
#pragma unroll
        for (int h = 0; h < 4; ++h) skf[s][h] = splat2(0.f);
    {
        const float4* mrow = (const float4*)m;
        const int* ipd = inv_s + eo * 17;
        const float* sp = sph_s + eo * 113;

        float4 c0 = make_float4(0.f, 0.f, 0.f, 0.f), c1 = c0;
        {
            int t = ipd[0];
            if ((unsigned)t < (unsigned)NTRIP) {
                const float4* tp = mrow + (size_t)t * 32 + oco * 2;
                c0 = tp[0]; c1 = tp[1];
            }
        }
#pragma unroll
        for (int k = 0; k < 16; ++k) {
            float4 n0 = make_float4(0.f, 0.f, 0.f, 0.f), n1 = n0;
            if (k < 15) {
                int t = ipd[k + 1];
                if ((unsigned)t < (unsigned)NTRIP) {
                    const float4* tp = mrow + (size_t)t * 32 + oco * 2;
                    n0 = tp[0]; n1 = tp[1];
                }
            }
            v2f mv[4];
            mv[0].x = c0.x; mv[0].y = c0.y;
            mv[1].x = c0.z; mv[1].y = c0.w;
            mv[2].x = c1.x; mv[2].y = c1.y;
            mv[3].x = c1.z; mv[3].y = c1.w;
#pragma unroll
            for (int s = 0; s < NSPH; ++s) {
                float cs = sp[s * 16 + k];
#pragma unroll
                for (int h = 0; h < 4; ++h)
                    skf[s][h] = __builtin_elementwise_fma(splat2(cs), mv[h], skf[s][h]);
            }
            c0 = n0; c1 = n1;
        }
    }

    // build one A-frag uint4 (edge eo, embs oco*8..+7, interm chunk rv4) at
    // a_s unit wid*65+lane (contiguous per wave -> conflict-free)
    auto buildChunk = [&](const uint4 rv4, uint4* dstbuf) {
        float rv[NSPH];
        rv[0] = __uint_as_float(rv4.x << 16);
        rv[1] = __uint_as_float(rv4.x & 0xffff0000u);
        rv[2] = __uint_as_float(rv4.y << 16);
        rv[3] = __uint_as_float(rv4.y & 0xffff0000u);
        rv[4] = __uint_as_float(rv4.z << 16);
        rv[5] = __uint_as_float(rv4.z & 0xffff0000u);
        rv[6] = __uint_as_float(rv4.w << 16);
        v2f v[4];
#pragma unroll
        for (int h = 0; h < 4; ++h) v[h] = splat2(rv[0]) * skf[0][h];
#pragma unroll
        for (int s = 1; s < NSPH; ++s)
#pragma unroll
            for (int h = 0; h < 4; ++h)
                v[h] = __builtin_elementwise_fma(splat2(rv[s]), skf[s][h], v[h]);
        dstbuf[wid * 65 + lane] = make_uint4(bf16pair(v[0].x, v[0].y), bf16pair(v[1].x, v[1].y),
                                             bf16pair(v[2].x, v[2].y), bf16pair(v[3].x, v[3].y));
    };

    auto mfmaStep = [&](const uint4* abuf) {
#pragma unroll
        for (int ksl = 0; ksl < 4; ++ksl) {
            short8 a0 = __builtin_bit_cast(short8, abuf[ksl * 65 + lane]);
            short8 a1 = __builtin_bit_cast(short8, abuf[(4 + ksl) * 65 + lane]);
            short8 bb = __builtin_bit_cast(short8, wf[ksl]);
            acc[0] = __builtin_amdgcn_mfma_f32_16x16x32_bf16(a0, bb, acc[0], 0, 0, 0);
            acc[1] = __builtin_amdgcn_mfma_f32_16x16x32_bf16(a1, bb, acc[1], 0, 0, 0);
        }
    };

    __syncthreads();            // scratch (inv_s/sph_s) dead; a_s reusable
    buildChunk(rpA, a_s[0]);    // chunk 0
    rpA = rpg[(size_t)2 * NEDGES];
    __syncthreads();

    for (int c = 0; c < 64; c += 2) {
        // even: MFMA chunk c (buf0), build chunk c+1 (buf1)
        buildChunk(rpB, a_s[1]);
        if (c + 3 < 64) rpB = rpg[(size_t)(c + 3) * NEDGES];
        mfmaStep(a_s[0]);
        __syncthreads();
#pragma unroll
        for (int ksl = 0; ksl < 4; ++ksl)      // post-barrier B-frags, chunk c+1
            wf[ksl] = wbase[(size_t)((c + 1) * 4 + ksl) * 64];

        // odd: MFMA chunk c+1 (buf1), build chunk c+2 (buf0)
        if (c + 2 < 64) {
            buildChunk(rpA, a_s[0]);
            if (c + 4 < 64) rpA = rpg[(size_t)(c + 4) * NEDGES];
        }
        mfmaStep(a_s[1]);
        __syncthreads();
        if (c + 2 < 64) {
#pragma unroll
            for (int ksl = 0; ksl < 4; ++ksl)  // post-barrier B-frags, chunk c+2
                wf[ksl] = wbase[(size_t)((c + 2) * 4 + ksl) * 64];
        }
    }

    // epilogue: C/D col = lane&15, row = (lane>>4)*4 + r
    const int col = lane & 15, r0 = (lane >> 4) * 4;
#pragma unroll
    for (int h = 0; h < 2; ++h) {
        size_t ebase = e0 + (size_t)h * 16 + r0;
#pragma unroll
        for (int r = 0; r < 4; ++r)
            out[(ebase + r) * UNITS + wid * 16 + col] = acc[h][r];
    }
}

extern "C" void kernel_launch(void* const* d_in, const int* in_sizes, int n_in,
                              void* d_out, int out_size, void* d_ws, size_t ws_size,
                              hipStream_t stream) {
    const float* rbf = (const float*)d_in[0];
    const float* sph = (const float*)d_in[1];
    const float* m   = (const float*)d_in[2];
    const float* w   = (const float*)d_in[3];
    const int*   idr = (const int*)d_in[4];
    const int*   kix = (const int*)d_in[5];
    float* out = (float*)d_out;

    // ws: inv (1.28 MB, pad to 0x140000) | w2f (2 MB) | rpad2 (20.48 MB)
    int*   inv   = (int*)d_ws;
    uint4* w2f   = (uint4*)((char*)d_ws + 0x140000);
    uint4* rpad2 = (uint4*)((char*)d_ws + 0x340000);

    prep<<<SC_BLOCKS + W_BLOCKS + RP_BLOCKS, 256, 0, stream>>>(idr, kix, inv, w, w2f, rbf, rpad2);
    fused_all<<<NEDGES / 32, 512, 0, stream>>>(sph, m, inv, w2f, rpad2, out);
}

// Round 6
// 425.264 us; speedup vs baseline: 1.1800x; 1.0013x over previous
//
#include <hip/hip_runtime.h>

#define NEDGES 20000
#define KMAX 16
#define NTRIP (NEDGES*KMAX)
#define EMB 128
#define INTERM 64
#define NSPH 7
#define UNITS 128
#define KSTEPS 256               // K = 8192 / 32

#define SC_BLOCKS (NTRIP/256)    // 1250
#define W_BLOCKS  512
#define RP_BLOCKS (NEDGES/16)    // 1250

typedef __attribute__((ext_vector_type(8))) short short8;
typedef __attribute__((ext_vector_type(4))) float floatx4;
typedef __attribute__((ext_vector_type(2))) float v2f;

__device__ __forceinline__ unsigned bf16pair(float a, float b) {
    unsigned ua = __float_as_uint(a), ub = __float_as_uint(b);
    ua = (ua + 0x7fffu + ((ua >> 16) & 1u)) >> 16;
    ub = (ub + 0x7fffu + ((ub >> 16) & 1u)) & 0xffff0000u;
    return ua | ub;
}
__device__ __forceinline__ v2f splat2(float f) { v2f r; r.x = f; r.y = f; return r; }

// prep roles: [0,1250) scatter-inverse; [1250,1762) weight->bf16 B-frags;
// [1762,3012) rbf fp32 (e,i,7) -> bf16 rpad2[i][e], LDS-staged per 16 edges
// (coalesced float4 reads; padded-stride LDS; 256B-chunk writes).
// No memset needed: (id_reduce,Kidx) pairs cover all slots; fused_all also
// bounds-checks t.
__global__ __launch_bounds__(256)
void prep(const int* __restrict__ idr, const int* __restrict__ kix,
          int* __restrict__ inv, const float* __restrict__ w,
          uint4* __restrict__ w2f, const float* __restrict__ rbf,
          uint4* __restrict__ rpad2) {
    __shared__ float lr[16 * 452];    // 28.9 KB, stride 452 (16B-aligned, 2-way banks)
    const int b = blockIdx.x, tid = threadIdx.x;
    if (b < SC_BLOCKS) {
        int t = b * 256 + tid;
        int e = idr[t], k = kix[t];
        if ((unsigned)e < NEDGES && (unsigned)k < KMAX)
            inv[e * KMAX + k] = t;
    } else if (b < SC_BLOCKS + W_BLOCKS) {
        // weight (emb, interm, o) fp32 -> bf16 MFMA B-fragment order.
        // uint4 idx = (nt*256 + ks)*64 + lane; elem j: k = ks*32 + (lane>>4)*8 + j,
        // o = nt*16 + (lane&15); k = i*128 + emb.
        int idx  = (b - SC_BLOCKS) * 256 + tid;
        int lane = idx & 63;
        int ks   = (idx >> 6) & 255;
        int nt   = idx >> 14;
        int o  = nt * 16 + (lane & 15);
        int kb = ks * 32 + (lane >> 4) * 8;
        unsigned pk[4];
#pragma unroll
        for (int jj = 0; jj < 4; ++jj) {
            int k0 = kb + 2 * jj;
            int i0 = k0 >> 7, em0 = k0 & 127;
            int i1 = (k0 + 1) >> 7, em1 = (k0 + 1) & 127;
            float f0 = w[((size_t)em0 * INTERM + i0) * UNITS + o];
            float f1 = w[((size_t)em1 * INTERM + i1) * UNITS + o];
            pk[jj] = bf16pair(f0, f1);
        }
        w2f[idx] = make_uint4(pk[0], pk[1], pk[2], pk[3]);
    } else {
        int rb = b - (SC_BLOCKS + W_BLOCKS);
        const float4* rg = (const float4*)(rbf + (size_t)rb * 16 * 448);
        for (int j = tid; j < 1792; j += 256) {
            float4 v = rg[j];
            int e = j / 112, idx = j - e * 112;
            *(float4*)&lr[e * 452 + idx * 4] = v;
        }
        __syncthreads();
        int e = tid & 15, ib = tid >> 4;
#pragma unroll
        for (int r = 0; r < 4; ++r) {
            int i = r * 16 + ib;
            const float* s = &lr[e * 452 + i * 7];
            rpad2[(size_t)i * NEDGES + rb * 16 + e] =
                make_uint4(bf16pair(s[0], s[1]), bf16pair(s[2], s[3]),
                           bf16pair(s[4], s[5]), bf16pair(s[6], 0.f));
        }
    }
}

// fused_all: block = 32 edges x N=128 x full K. 512 threads (8 waves, wave = nt).
// Thread ownership chosen so wave wid builds exactly a_s frag-row wid:
//   eo = (wid>>2)*16 + (lane&15), oco = (wid&3)*4 + (lane>>4).
// Then BOTH the a_s write (wid*65+lane) and reads (fr*65+lane) are the
// canonical 64-consecutive-uint4 pattern -> conflict-free, no swizzle.
// Register budget: amdgpu_waves_per_eu(2,2) -> VGPR cap 512/2 = 256. The
// peak live set is ~160-190 regs (skf 56 + wf 16 + rp 8 + acc 8 + unrolled
// MFMA operand temps + addressing). History: __launch_bounds__ second arg
// behaves as min BLOCKS/CU on this toolchain — (512,4) capped at 64 regs
// (R3: 290 MB spill), (512,2)/default capped at 128 (R4/R5: 81 MB spill,
// VGPR_Count pinned at exactly 128). The explicit attribute bypasses that.
// 2 waves/SIMD (1 block/CU) suffices: per-chunk critical resource is the
// per-CU LDS pipe (~860 cyc/chunk), which 8 waves saturate.
__global__ __launch_bounds__(512) __attribute__((amdgpu_waves_per_eu(2, 2)))
void fused_all(const float* __restrict__ sph, const float* __restrict__ m,
               const int* __restrict__ inv, const uint4* __restrict__ w2f,
               const uint4* __restrict__ rpad2, float* __restrict__ out) {
    __shared__ uint4 a_s[2][520];                 // 16640 B, frag-row stride 65
    int*   inv_s = (int*)a_s;                     // scratch: 32x17 ints = 2176 B
    float* sph_s = (float*)((char*)a_s + 2176);   // scratch: 32x113 f32 = 14464 B

    const int tid = threadIdx.x;
    const size_t e0 = (size_t)blockIdx.x * 32;
    const int lane = tid & 63, wid = tid >> 6;    // wid = nt 0..7
    const int eo  = (wid >> 2) * 16 + (lane & 15);   // owned edge 0..31
    const int oco = (wid & 3) * 4 + (lane >> 4);     // owned emb octet 0..15

    // stage inv + sph into padded scratch (odd strides 17/113: conflict-free)
    {
        int e = tid >> 4, k = tid & 15;
        inv_s[e * 17 + k] = inv[e0 * 16 + tid];
    }
    for (int j = tid; j < 32 * 112; j += 512) {
        int e = j / 112, r = j - e * 112;
        sph_s[e * 113 + r] = sph[e0 * 112 + j];
    }
    __syncthreads();

    // long-latency prefetches issued here so they hide under the m-gather
    // (and are NOT drained by the staging barrier above)
    floatx4 acc[2] = {{0.f, 0.f, 0.f, 0.f}, {0.f, 0.f, 0.f, 0.f}};
    uint4 wf[4];
    const uint4* wbase = w2f + ((size_t)wid * KSTEPS) * 64 + lane;
#pragma unroll
    for (int ksl = 0; ksl < 4; ++ksl) wf[ksl] = wbase[(size_t)ksl * 64];
    const uint4* rpg = rpad2 + (e0 + eo);
    uint4 rpA = rpg[0], rpB = rpg[(size_t)1 * NEDGES];

    // fused build_sumk: skf[s][h] = sum_k sph[eo][s][k] * m[inv[eo][k]][oco*8+2h..+1]
    // 2-deep m pipeline; inv read per-k from LDS (prologue-only liveness).
    v2f skf[NSPH][4];
#pragma unroll
    for (int s = 0; s < NSPH; ++s)
#pragma unroll
        for (int h = 0; h < 4; ++h) skf[s][h] = splat2(0.f);
    {
        const float4* mrow = (const float4*)m;
        const int* ipd = inv_s + eo * 17;
        const float* sp = sph_s + eo * 113;

        float4 c0 = make_float4(0.f, 0.f, 0.f, 0.f), c1 = c0;
        {
            int t = ipd[0];
            if ((unsigned)t < (unsigned)NTRIP) {
                const float4* tp = mrow + (size_t)t * 32 + oco * 2;
                c0 = tp[0]; c1 = tp[1];
            }
        }
#pragma unroll
        for (int k = 0; k < 16; ++k) {
            float4 n0 = make_float4(0.f, 0.f, 0.f, 0.f), n1 = n0;
            if (k < 15) {
                int t = ipd[k + 1];
                if ((unsigned)t < (unsigned)NTRIP) {
                    const float4* tp = mrow + (size_t)t * 32 + oco * 2;
                    n0 = tp[0]; n1 = tp[1];
                }
            }
            v2f mv[4];
            mv[0].x = c0.x; mv[0].y = c0.y;
            mv[1].x = c0.z; mv[1].y = c0.w;
            mv[2].x = c1.x; mv[2].y = c1.y;
            mv[3].x = c1.z; mv[3].y = c1.w;
#pragma unroll
            for (int s = 0; s < NSPH; ++s) {
                float cs = sp[s * 16 + k];
#pragma unroll
                for (int h = 0; h < 4; ++h)
                    skf[s][h] = __builtin_elementwise_fma(splat2(cs), mv[h], skf[s][h]);
            }
            c0 = n0; c1 = n1;
        }
    }

    // build one A-frag uint4 (edge eo, embs oco*8..+7, interm chunk rv4) at
    // a_s unit wid*65+lane (contiguous per wave -> conflict-free)
    auto buildChunk = [&](const uint4 rv4, uint4* dstbuf) {
        float rv[NSPH];
        rv[0] = __uint_as_float(rv4.x << 16);
        rv[1] = __uint_as_float(rv4.x & 0xffff0000u);
        rv[2] = __uint_as_float(rv4.y << 16);
        rv[3] = __uint_as_float(rv4.y & 0xffff0000u);
        rv[4] = __uint_as_float(rv4.z << 16);
        rv[5] = __uint_as_float(rv4.z & 0xffff0000u);
        rv[6] = __uint_as_float(rv4.w << 16);
        v2f v[4];
#pragma unroll
        for (int h = 0; h < 4; ++h) v[h] = splat2(rv[0]) * skf[0][h];
#pragma unroll
        for (int s = 1; s < NSPH; ++s)
#pragma unroll
            for (int h = 0; h < 4; ++h)
                v[h] = __builtin_elementwise_fma(splat2(rv[s]), skf[s][h], v[h]);
        dstbuf[wid * 65 + lane] = make_uint4(bf16pair(v[0].x, v[0].y), bf16pair(v[1].x, v[1].y),
                                             bf16pair(v[2].x, v[2].y), bf16pair(v[3].x, v[3].y));
    };

    auto mfmaStep = [&](const uint4* abuf) {
#pragma unroll
        for (int ksl = 0; ksl < 4; ++ksl) {
            short8 a0 = __builtin_bit_cast(short8, abuf[ksl * 65 + lane]);
            short8 a1 = __builtin_bit_cast(short8, abuf[(4 + ksl) * 65 + lane]);
            short8 bb = __builtin_bit_cast(short8, wf[ksl]);
            acc[0] = __builtin_amdgcn_mfma_f32_16x16x32_bf16(a0, bb, acc[0], 0, 0, 0);
            acc[1] = __builtin_amdgcn_mfma_f32_16x16x32_bf16(a1, bb, acc[1], 0, 0, 0);
        }
    };

    __syncthreads();            // scratch (inv_s/sph_s) dead; a_s reusable
    buildChunk(rpA, a_s[0]);    // chunk 0
    rpA = rpg[(size_t)2 * NEDGES];
    __syncthreads();

    for (int c = 0; c < 64; c += 2) {
        // even: MFMA chunk c (buf0), build chunk c+1 (buf1)
        buildChunk(rpB, a_s[1]);
        if (c + 3 < 64) rpB = rpg[(size_t)(c + 3) * NEDGES];
        mfmaStep(a_s[0]);
        __syncthreads();
#pragma unroll
        for (int ksl = 0; ksl < 4; ++ksl)      // post-barrier B-frags, chunk c+1
            wf[ksl] = wbase[(size_t)((c + 1) * 4 + ksl) * 64];

        // odd: MFMA chunk c+1 (buf1), build chunk c+2 (buf0)
        if (c + 2 < 64) {
            buildChunk(rpA, a_s[0]);
            if (c + 4 < 64) rpA = rpg[(size_t)(c + 4) * NEDGES];
        }
        mfmaStep(a_s[1]);
        __syncthreads();
        if (c + 2 < 64) {
#pragma unroll
            for (int ksl = 0; ksl < 4; ++ksl)  // post-barrier B-frags, chunk c+2
                wf[ksl] = wbase[(size_t)((c + 2) * 4 + ksl) * 64];
        }
    }

    // epilogue: C/D col = lane&15, row = (lane>>4)*4 + r
    const int col = lane & 15, r0 = (lane >> 4) * 4;
#pragma unroll
    for (int h = 0; h < 2; ++h) {
        size_t ebase = e0 + (size_t)h * 16 + r0;
#pragma unroll
        for (int r = 0; r < 4; ++r)
            out[(ebase + r) * UNITS + wid * 16 + col] = acc[h][r];
    }
}

extern "C" void kernel_launch(void* const* d_in, const int* in_sizes, int n_in,
                              void* d_out, int out_size, void* d_ws, size_t ws_size,
                              hipStream_t stream) {
    const float* rbf = (const float*)d_in[0];
    const float* sph = (const float*)d_in[1];
    const float* m   = (const float*)d_in[2];
    const float* w   = (const float*)d_in[3];
    const int*   idr = (const int*)d_in[4];
    const int*   kix = (const int*)d_in[5];
    float* out = (float*)d_out;

    // ws: inv (1.28 MB, pad to 0x140000) | w2f (2 MB) | rpad2 (20.48 MB)
    int*   inv   = (int*)d_ws;
    uint4* w2f   = (uint4*)((char*)d_ws + 0x140000);
    uint4* rpad2 = (uint4*)((char*)d_ws + 0x340000);

    prep<<<SC_BLOCKS + W_BLOCKS + RP_BLOCKS, 256, 0, stream>>>(idr, kix, inv, w, w2f, rbf, rpad2);
    fused_all<<<NEDGES / 32, 512, 0, stream>>>(sph, m, inv, w2f, rpad2, out);
}